// Round 1
// baseline (2208.435 us; speedup 1.0000x reference)
//
#include <hip/hip_runtime.h>
#include <hip/hip_bf16.h>

// ---------------------------------------------------------------------------
// SCSAttention: pointwise-conv chains + small attention, f32 baseline.
// Shapes: B=4 F=8 C=256 CIN=2048 CH=128 W=H=7, N=32 images, 49 px, 1568 tokens.
// ---------------------------------------------------------------------------

#define TOKENS 1568   // 32*49
#define CIN    2048
#define CMID   256
#define CH     128
#define SEQ    392    // 8*49
#define NPIX   49

constexpr int BM = 64, BN = 64, BK = 32;

#define EPI_NONE  0
#define EPI_V     1
#define EPI_FINAL 2

// Generic f32 GEMM: C[m][n] = sum_k A[m*lda+k] * W[n*ldw+k] (+ bias[n]) (+ epilogue)
template<int EPI>
__global__ __launch_bounds__(256)
void gemm_k(const float* __restrict__ Ag, int lda, long sA,
            const float* __restrict__ Wg, int ldw, long sW,
            const float* __restrict__ bias,
            float* __restrict__ Cg, int ldc, long sC,
            int M, int N, int K,
            const float* __restrict__ ex1,   // EPI_V: pos_embed ; EPI_FINAL: x
            const float* __restrict__ ex2,   // EPI_FINAL: gamma
            float* __restrict__ out2)        // EPI_V: VT ; EPI_FINAL: d_out
{
    const int bz = blockIdx.z;
    const float* A = Ag + (long)bz * sA;
    const float* W = Wg + (long)bz * sW;
    float* C = Cg ? (Cg + (long)bz * sC) : nullptr;

    __shared__ float As[BK][BM + 4];   // transposed tiles: [k][m], padded for b128
    __shared__ float Ws[BK][BN + 4];

    const int tid = threadIdx.x;
    const int tx = tid & 15, ty = tid >> 4;
    const int row0 = blockIdx.y * BM;
    const int col0 = blockIdx.x * BN;

    float acc[4][4] = {};

    for (int k0 = 0; k0 < K; k0 += BK) {
#pragma unroll
        for (int i = 0; i < 8; ++i) {
            int idx = tid + 256 * i;       // 0..2047
            int r  = idx >> 5;             // 0..63
            int kk = idx & 31;
            int gk = k0 + kk;
            float va = 0.f, vw = 0.f;
            if (gk < K) {
                int gm = row0 + r;
                if (gm < M) va = A[(long)gm * lda + gk];
                int gn = col0 + r;
                if (gn < N) vw = W[(long)gn * ldw + gk];
            }
            As[kk][r] = va;
            Ws[kk][r] = vw;
        }
        __syncthreads();
#pragma unroll
        for (int kk = 0; kk < BK; ++kk) {
            float a[4], w[4];
#pragma unroll
            for (int i = 0; i < 4; ++i) a[i] = As[kk][ty * 4 + i];
#pragma unroll
            for (int j = 0; j < 4; ++j) w[j] = Ws[kk][tx * 4 + j];
#pragma unroll
            for (int i = 0; i < 4; ++i)
#pragma unroll
                for (int j = 0; j < 4; ++j)
                    acc[i][j] = fmaf(a[i], w[j], acc[i][j]);
        }
        __syncthreads();
    }

#pragma unroll
    for (int i = 0; i < 4; ++i) {
        int m = row0 + ty * 4 + i;
        if (m >= M) continue;
#pragma unroll
        for (int j = 0; j < 4; ++j) {
            int n = col0 + tx * 4 + j;
            if (n >= N) continue;
            float v = acc[i][j];
            if (bias) v += bias[n];
            if (EPI == EPI_NONE) {
                C[(long)m * ldc + n] = v;
            } else if (EPI == EPI_V) {
                // m = token t, n = channel c; add pos embed, store V transposed [b][c][s]
                int f = (m / NPIX) & 7;
                int p = m % NPIX;
                v += ex1[f * (CMID * NPIX) + n * NPIX + p];
                int b = m / SEQ;
                int s = m % SEQ;
                out2[(long)b * (CMID * SEQ) + (long)n * SEQ + s] = v;
            } else {
                // EPI_FINAL: m = token t, n = out channel o
                int nimg = m / NPIX;
                int p = m % NPIX;
                long xi = (long)nimg * (CIN * NPIX) + (long)n * NPIX + p;
                float x = ex1[xi];
                float g = ex2[0];
                out2[xi] = (g * v + x) * v + x;
            }
        }
    }
}

// Transpose [32][2048][49] (NCHW) -> token-major [1568][2048]
__global__ __launch_bounds__(256)
void transpose_cp(const float* __restrict__ x, const float* __restrict__ dXin,
                  float* __restrict__ Xt, float* __restrict__ DXt)
{
    __shared__ float tile[64][51];
    int n  = blockIdx.x;          // 32
    int c0 = blockIdx.y * 64;     // 32 blocks
    const float* src = blockIdx.z ? dXin : x;
    float* dst       = blockIdx.z ? DXt : Xt;
    const float* s = src + (long)n * (CIN * NPIX) + (long)c0 * NPIX;
    for (int idx = threadIdx.x; idx < 64 * NPIX; idx += 256) {
        int cl = idx / NPIX, p = idx % NPIX;
        tile[cl][p] = s[cl * NPIX + p];
    }
    __syncthreads();
    for (int idx = threadIdx.x; idx < NPIX * 64; idx += 256) {
        int p = idx >> 6, cl = idx & 63;
        dst[((long)(n * NPIX + p)) * CIN + c0 + cl] = tile[cl][p];
    }
}

// cX[o] = sum_c w_value[o][c]*b_l1down[c] + b_l1up[o]   (and _Y variant)
__global__ __launch_bounds__(256)
void prep_c(const float* __restrict__ w_value,
            const float* __restrict__ bdX, const float* __restrict__ buX,
            const float* __restrict__ bdY, const float* __restrict__ buY,
            float* __restrict__ cX, float* __restrict__ cY)
{
    int o = blockIdx.x * 256 + threadIdx.x;   // grid.x = 8 -> o<2048
    const float* bd = blockIdx.y ? bdY : bdX;
    const float* bu = blockIdx.y ? buY : buX;
    float* out      = blockIdx.y ? cY : cX;
    float acc = 0.f;
    const float* wr = w_value + (long)o * CMID;
    for (int c = 0; c < CMID; ++c) acc = fmaf(wr[c], bd[c], acc);
    out[o] = acc + bu[o];
}

// eX[j] = sum_o w_l2down[j][o]*cX[o] + b_l2down[j]   (wave per j)
__global__ __launch_bounds__(256)
void prep_e(const float* __restrict__ WX, const float* __restrict__ bX,
            const float* __restrict__ cX,
            const float* __restrict__ WY, const float* __restrict__ bY,
            const float* __restrict__ cY,
            float* __restrict__ eX, float* __restrict__ eY)
{
    const float* W = blockIdx.y ? WY : WX;
    const float* b = blockIdx.y ? bY : bX;
    const float* c = blockIdx.y ? cY : cX;
    float* e       = blockIdx.y ? eY : eX;
    int wave = threadIdx.x >> 6;
    int lane = threadIdx.x & 63;
    int j = blockIdx.x * 4 + wave;            // grid.x = 64 -> j<256
    float acc = 0.f;
    const float* wr = W + (long)j * CIN;
    for (int o = lane; o < CIN; o += 64) acc = fmaf(wr[o], c[o], acc);
    for (int off = 32; off; off >>= 1) acc += __shfl_down(acc, off, 64);
    if (lane == 0) e[j] = acc + b[j];
}

// KmatT[b][m][ci] = k-permute gather from Kt[t][c]
__global__ __launch_bounds__(256)
void permute_k(const float* __restrict__ Kt, float* __restrict__ KmatT)
{
    int idx = blockIdx.x * 256 + threadIdx.x;      // grid = 1568 -> 4*392*256
    int b  = idx / (SEQ * CMID);
    int r  = idx % (SEQ * CMID);
    int m  = r / CMID;
    int ci = r % CMID;
    int flat = ci * SEQ + m;
    int wd = flat / 14336;           // 8*7*256
    int f  = (flat / 1792) & 7;      // 7*256
    int hd = (flat / 256) % 7;
    int c  = flat & 255;
    int p  = wd * 7 + hd;
    int t  = (b * 8 + f) * NPIX + p;
    KmatT[idx] = Kt[(long)t * CMID + c];
}

// Row-wise softmax over L[1568][392], one wave per row
__global__ __launch_bounds__(64)
void softmax_rows(float* __restrict__ L)
{
    int row = blockIdx.x;
    float* r = L + (long)row * SEQ;
    int lane = threadIdx.x;
    float v[7];
    float mx = -1e30f;
#pragma unroll
    for (int i = 0; i < 7; ++i) {
        int idx = lane + i * 64;
        v[i] = (idx < SEQ) ? r[idx] : -1e30f;
        mx = fmaxf(mx, v[i]);
    }
    for (int off = 32; off; off >>= 1) mx = fmaxf(mx, __shfl_xor(mx, off, 64));
    float sum = 0.f;
#pragma unroll
    for (int i = 0; i < 7; ++i) { v[i] = __expf(v[i] - mx); sum += v[i]; }
    for (int off = 32; off; off >>= 1) sum += __shfl_xor(sum, off, 64);
    float inv = 1.f / sum;
#pragma unroll
    for (int i = 0; i < 7; ++i) {
        int idx = lane + i * 64;
        if (idx < SEQ) r[idx] = v[i] * inv;
    }
}

extern "C" void kernel_launch(void* const* d_in, const int* in_sizes, int n_in,
                              void* d_out, int out_size, void* d_ws, size_t ws_size,
                              hipStream_t stream)
{
    const float* x        = (const float*)d_in[0];
    const float* domainX  = (const float*)d_in[1];
    // d_in[2..4] (domainY, w_pre, b_pre) feed only dead code — skipped.
    const float* w_conv3  = (const float*)d_in[5];
    const float* b_conv3  = (const float*)d_in[6];
    const float* w_value  = (const float*)d_in[7];
    const float* b_value  = (const float*)d_in[8];
    const float* b_l1down   = (const float*)d_in[9];
    const float* b_l1up     = (const float*)d_in[10];
    const float* b_l1down_Y = (const float*)d_in[11];
    const float* b_l1up_Y   = (const float*)d_in[12];
    const float* w_l2down   = (const float*)d_in[13];
    const float* b_l2down   = (const float*)d_in[14];
    const float* w_l2up     = (const float*)d_in[15];
    const float* b_l2up     = (const float*)d_in[16];
    const float* w_l2down_Y = (const float*)d_in[17];
    const float* b_l2down_Y = (const float*)d_in[18];
    const float* w_l2up_Y   = (const float*)d_in[19];
    const float* b_l2up_Y   = (const float*)d_in[20];
    const float* w_c11 = (const float*)d_in[21];
    const float* b_c11 = (const float*)d_in[22];
    const float* w_c12 = (const float*)d_in[23];
    const float* b_c12 = (const float*)d_in[24];
    const float* w_c21 = (const float*)d_in[25];
    const float* b_c21 = (const float*)d_in[26];
    const float* w_c22 = (const float*)d_in[27];
    const float* b_c22 = (const float*)d_in[28];
    const float* pos   = (const float*)d_in[29];
    const float* gamma = (const float*)d_in[30];
    float* out = (float*)d_out;

    float* ws = (float*)d_ws;
    // workspace layout (floats); buffers reused where lifetimes allow
    const size_t oXt  = 0;                         // [1568][2048] x token-major
    const size_t oDXt = 3211264;                   // domainX token-major; later dX
    const size_t oU0  = 6422528;                   // U0; later dY
    const size_t oP0  = 9633792;                   // P0; later D1X        [1568][256]
    const size_t oD1Y = 10035200;                  // [1568][256]
    const size_t ocX  = 10436608;                  // 2048
    const size_t ocY  = 10438656;                  // 2048
    const size_t oeX  = 10440704;                  // 256
    const size_t oeY  = 10440960;                  // 256
    const size_t oQ   = 10441216;                  // [1568][256]
    const size_t oKt  = 10842624;                  // [1568][256]
    const size_t oKmT = 11244032;                  // [4][392][256]
    const size_t oVT  = 11645440;                  // [4][256][392]
    const size_t oL   = 12046848;                  // [4][392][392]
    const size_t oO   = 12661504;                  // [1568][256]

    // 1. token-major transposes of x and domainX
    transpose_cp<<<dim3(32, 32, 2), 256, 0, stream>>>(x, domainX, ws + oXt, ws + oDXt);

    // 2. folded layer-1 bias vectors cX/cY
    prep_c<<<dim3(8, 2), 256, 0, stream>>>(w_value, b_l1down, b_l1up,
                                           b_l1down_Y, b_l1up_Y, ws + ocX, ws + ocY);

    // 3. P0 = DXt @ w_conv3^T           [1568][256]
    gemm_k<EPI_NONE><<<dim3(4, 25, 1), 256, 0, stream>>>(
        ws + oDXt, CIN, 0, w_conv3, CIN, 0, nullptr,
        ws + oP0, CMID, 0, TOKENS, CMID, CIN, nullptr, nullptr, nullptr);

    // 4. U0 = P0 @ w_value^T            [1568][2048]
    gemm_k<EPI_NONE><<<dim3(32, 25, 1), 256, 0, stream>>>(
        ws + oP0, CMID, 0, w_value, CMID, 0, nullptr,
        ws + oU0, CIN, 0, TOKENS, CIN, CMID, nullptr, nullptr, nullptr);

    // 5. folded layer-2 bias vectors eX/eY
    prep_e<<<dim3(64, 2), 256, 0, stream>>>(w_l2down, b_l2down, ws + ocX,
                                            w_l2down_Y, b_l2down_Y, ws + ocY,
                                            ws + oeX, ws + oeY);

    // 6. D1X = U0 @ w_l2down^T + eX     (into P0 slot)
    gemm_k<EPI_NONE><<<dim3(4, 25, 1), 256, 0, stream>>>(
        ws + oU0, CIN, 0, w_l2down, CIN, 0, ws + oeX,
        ws + oP0, CMID, 0, TOKENS, CMID, CIN, nullptr, nullptr, nullptr);

    // 7. D1Y = U0 @ w_l2down_Y^T + eY
    gemm_k<EPI_NONE><<<dim3(4, 25, 1), 256, 0, stream>>>(
        ws + oU0, CIN, 0, w_l2down_Y, CIN, 0, ws + oeY,
        ws + oD1Y, CMID, 0, TOKENS, CMID, CIN, nullptr, nullptr, nullptr);

    // 8. dX = D1X @ w_l2up^T + b_l2up   (into DXt slot)
    gemm_k<EPI_NONE><<<dim3(32, 25, 1), 256, 0, stream>>>(
        ws + oP0, CMID, 0, w_l2up, CMID, 0, b_l2up,
        ws + oDXt, CIN, 0, TOKENS, CIN, CMID, nullptr, nullptr, nullptr);

    // 9. dY = D1Y @ w_l2up_Y^T + b_l2up_Y  (into U0 slot)
    gemm_k<EPI_NONE><<<dim3(32, 25, 1), 256, 0, stream>>>(
        ws + oD1Y, CMID, 0, w_l2up_Y, CMID, 0, b_l2up_Y,
        ws + oU0, CIN, 0, TOKENS, CIN, CMID, nullptr, nullptr, nullptr);

    // 10/11. Q = [x@w_c11^T + b_c11 | dY@w_c12^T + b_c12]   [1568][256]
    gemm_k<EPI_NONE><<<dim3(2, 25, 1), 256, 0, stream>>>(
        ws + oXt, CIN, 0, w_c11, CIN, 0, b_c11,
        ws + oQ, CMID, 0, TOKENS, CH, CIN, nullptr, nullptr, nullptr);
    gemm_k<EPI_NONE><<<dim3(2, 25, 1), 256, 0, stream>>>(
        ws + oU0, CIN, 0, w_c12, CIN, 0, b_c12,
        ws + oQ + CH, CMID, 0, TOKENS, CH, CIN, nullptr, nullptr, nullptr);

    // 12/13. Kt = [x@w_c21^T + b_c21 | dX@w_c22^T + b_c22]
    gemm_k<EPI_NONE><<<dim3(2, 25, 1), 256, 0, stream>>>(
        ws + oXt, CIN, 0, w_c21, CIN, 0, b_c21,
        ws + oKt, CMID, 0, TOKENS, CH, CIN, nullptr, nullptr, nullptr);
    gemm_k<EPI_NONE><<<dim3(2, 25, 1), 256, 0, stream>>>(
        ws + oDXt, CIN, 0, w_c22, CIN, 0, b_c22,
        ws + oKt + CH, CMID, 0, TOKENS, CH, CIN, nullptr, nullptr, nullptr);

    // 14. V (transposed per batch): VT[b][c][s] = x@w_conv3^T + b_conv3 + pos
    gemm_k<EPI_V><<<dim3(4, 25, 1), 256, 0, stream>>>(
        ws + oXt, CIN, 0, w_conv3, CIN, 0, b_conv3,
        nullptr, 0, 0, TOKENS, CMID, CIN, pos, nullptr, ws + oVT);

    // 15. K permute gather
    permute_k<<<dim3(1568), 256, 0, stream>>>(ws + oKt, ws + oKmT);

    // 16. logits L[b] = Q[b] @ KmatT[b]^T   (batched, M=N=392, K=256)
    gemm_k<EPI_NONE><<<dim3(7, 7, 4), 256, 0, stream>>>(
        ws + oQ, CMID, SEQ * CMID, ws + oKmT, CMID, SEQ * CMID, nullptr,
        ws + oL, SEQ, SEQ * SEQ, SEQ, SEQ, CMID, nullptr, nullptr, nullptr);

    // 17. softmax rows
    softmax_rows<<<dim3(1568), 64, 0, stream>>>(ws + oL);

    // 18. O[b] = attn[b] @ V[b]   (A=[392][392], W=VT[b][256][392], K=392)
    gemm_k<EPI_NONE><<<dim3(4, 7, 4), 256, 0, stream>>>(
        ws + oL, SEQ, SEQ * SEQ, ws + oVT, SEQ, CMID * SEQ, nullptr,
        ws + oO, CMID, SEQ * CMID, SEQ, CMID, SEQ, nullptr, nullptr, nullptr);

    // 19. final: z = O @ w_value^T + b_value; out = (gamma*z + x)*z + x
    gemm_k<EPI_FINAL><<<dim3(32, 25, 1), 256, 0, stream>>>(
        ws + oO, CMID, 0, w_value, CMID, 0, b_value,
        nullptr, 0, 0, TOKENS, CIN, CMID, x, gamma, out);
}

// Round 2
// 227.185 us; speedup vs baseline: 9.7209x; 9.7209x over previous
//
#include <hip/hip_runtime.h>
#include <hip/hip_bf16.h>

// ---------------------------------------------------------------------------
// SCSAttention on MI355X: all GEMMs via mfma_f32_16x16x32_bf16.
// Sensitive path (Q/K -> logits) uses bf16x2 split 3-pass MFMA (~f32 accuracy);
// everything else plain bf16 1-pass.
// B=4 F=8 C=256 CIN=2048 CH=128 W=H=7 -> 32 imgs, 49 px, 1568 tokens, SEQ=392.
// ---------------------------------------------------------------------------

typedef __attribute__((ext_vector_type(8))) short short8;
typedef __attribute__((ext_vector_type(4))) float f32x4;

#define TOKENS 1568
#define SEQP   416          // 392 padded to multiple of 32

__device__ inline ushort f2bf(float f) {
    uint32_t u = __float_as_uint(f);
    u += 0x7fffu + ((u >> 16) & 1u);   // RNE
    return (ushort)(u >> 16);
}
__device__ inline float bf2f(ushort h) { return __uint_as_float(((uint32_t)h) << 16); }
__device__ inline void split2(float v, ushort& h, ushort& l) {
    h = f2bf(v);
    l = f2bf(v - bf2f(h));
}

struct EpiArgs {
    ushort* Ch; ushort* Cl;           // bf16 / split outputs
    float*  Cf;                       // f32 output (logits)
    ushort* Kh; ushort* Kl;           // G1: K region
    ushort* Vh;                       // G1: V region (bf16)
    const float* pos;                 // G1
    const float* x; const float* gamma; float* fout;   // FINAL
};

#define EPI_BF16  0
#define EPI_SPLIT 1
#define EPI_F32   2
#define EPI_G1    3
#define EPI_FINAL 4

// Tile 64x64, BK=32, 256 threads = 4 waves (2x2 of 32x32), each wave 2x2 16x16 frags.
template<int EPI, bool SPLIT>
__global__ __launch_bounds__(256)
void mgemm(const ushort* __restrict__ Ah, const ushort* __restrict__ Al,
           int lda, long sA,
           const ushort* __restrict__ Wh, const ushort* __restrict__ Wl,
           int ldw, long sW,
           const float* __restrict__ bias, long sB,
           int ldc, long sC,
           int M, int N, int K,
           EpiArgs ea)
{
    constexpr int LDS_W = 40;   // 32 + 8 pad: conflict-free ds_read_b128
    __shared__ ushort AshH[64 * LDS_W], WshH[64 * LDS_W];
    __shared__ ushort AshL[SPLIT ? 64 * LDS_W : 8], WshL[SPLIT ? 64 * LDS_W : 8];

    const int bz = blockIdx.z;
    const int tid = threadIdx.x;
    const int r  = tid >> 2;
    const int kq = (tid & 3) * 8;

    int gm = blockIdx.y * 64 + r; gm = gm < M ? gm : M - 1;
    int gn = blockIdx.x * 64 + r; gn = gn < N ? gn : N - 1;
    const ushort* gA = Ah + bz * sA + (long)gm * lda + kq;
    const ushort* gW = Wh + bz * sW + (long)gn * ldw + kq;
    const ushort* gAl = nullptr; const ushort* gWl = nullptr;
    if constexpr (SPLIT) {
        gAl = Al + bz * sA + (long)gm * lda + kq;
        gWl = Wl + bz * sW + (long)gn * ldw + kq;
    }

    short8 ra = *(const short8*)gA;
    short8 rw = *(const short8*)gW;
    short8 ral, rwl;
    if constexpr (SPLIT) { ral = *(const short8*)gAl; rwl = *(const short8*)gWl; }

    const int lane = tid & 63;
    const int wv = tid >> 6;
    const int wr = (wv >> 1) * 32, wc = (wv & 1) * 32;
    const int fr = lane & 15;
    const int kb = (lane >> 4) * 8;
    const int aoff0 = (wr + fr) * LDS_W + kb, aoff1 = aoff0 + 16 * LDS_W;
    const int boff0 = (wc + fr) * LDS_W + kb, boff1 = boff0 + 16 * LDS_W;
    const int sst = r * LDS_W + kq;

    f32x4 zero4 = {0.f, 0.f, 0.f, 0.f};
    f32x4 acc[2][2], acc2[2][2];
#pragma unroll
    for (int i = 0; i < 2; ++i)
#pragma unroll
        for (int j = 0; j < 2; ++j) { acc[i][j] = zero4; acc2[i][j] = zero4; }

    for (int k0 = 0; k0 < K; k0 += 32) {
        __syncthreads();
        *(short8*)&AshH[sst] = ra;
        *(short8*)&WshH[sst] = rw;
        if constexpr (SPLIT) { *(short8*)&AshL[sst] = ral; *(short8*)&WshL[sst] = rwl; }
        __syncthreads();
        if (k0 + 32 < K) {   // prefetch next K-tile; latency hides under MFMA below
            ra = *(const short8*)(gA + k0 + 32);
            rw = *(const short8*)(gW + k0 + 32);
            if constexpr (SPLIT) {
                ral = *(const short8*)(gAl + k0 + 32);
                rwl = *(const short8*)(gWl + k0 + 32);
            }
        }
        short8 fa[2], fb[2];
        fa[0] = *(short8*)&AshH[aoff0]; fa[1] = *(short8*)&AshH[aoff1];
        fb[0] = *(short8*)&WshH[boff0]; fb[1] = *(short8*)&WshH[boff1];
        short8 ga[2], gb[2];
        if constexpr (SPLIT) {
            ga[0] = *(short8*)&AshL[aoff0]; ga[1] = *(short8*)&AshL[aoff1];
            gb[0] = *(short8*)&WshL[boff0]; gb[1] = *(short8*)&WshL[boff1];
        }
#pragma unroll
        for (int mi = 0; mi < 2; ++mi)
#pragma unroll
            for (int ni = 0; ni < 2; ++ni) {
                acc[mi][ni] = __builtin_amdgcn_mfma_f32_16x16x32_bf16(fa[mi], fb[ni], acc[mi][ni], 0, 0, 0);
                if constexpr (SPLIT) {
                    acc2[mi][ni] = __builtin_amdgcn_mfma_f32_16x16x32_bf16(fa[mi], gb[ni], acc2[mi][ni], 0, 0, 0);
                    acc2[mi][ni] = __builtin_amdgcn_mfma_f32_16x16x32_bf16(ga[mi], fb[ni], acc2[mi][ni], 0, 0, 0);
                }
            }
    }

    const int row0 = blockIdx.y * 64, col0 = blockIdx.x * 64;
#pragma unroll
    for (int mi = 0; mi < 2; ++mi)
#pragma unroll
        for (int ni = 0; ni < 2; ++ni)
#pragma unroll
            for (int q = 0; q < 4; ++q) {
                int m = row0 + wr + mi * 16 + (lane >> 4) * 4 + q;
                int n = col0 + wc + ni * 16 + fr;
                if (m >= M || n >= N) continue;
                float v = acc[mi][ni][q];
                if constexpr (SPLIT) v += acc2[mi][ni][q];
                if (bias) v += bias[bz * sB + n];
                if constexpr (EPI == EPI_BF16) {
                    ea.Ch[bz * sC + (long)m * ldc + n] = f2bf(v);
                } else if constexpr (EPI == EPI_SPLIT) {
                    ushort h, l; split2(v, h, l);
                    long o = bz * sC + (long)m * ldc + n;
                    ea.Ch[o] = h; ea.Cl[o] = l;
                } else if constexpr (EPI == EPI_F32) {
                    ea.Cf[bz * sC + (long)m * ldc + n] = v;
                } else if constexpr (EPI == EPI_G1) {
                    if (n < 128) {
                        ushort h, l; split2(v, h, l);
                        long o = (long)m * 256 + n;
                        ea.Ch[o] = h; ea.Cl[o] = l;
                    } else if (n < 256) {
                        ushort h, l; split2(v, h, l);
                        long o = (long)m * 256 + (n - 128);
                        ea.Kh[o] = h; ea.Kl[o] = l;
                    } else {
                        int c = n - 256;
                        int f = (m / 49) & 7, p = m % 49;
                        v += ea.pos[f * (256 * 49) + c * 49 + p];
                        int b = m / 392, s = m % 392;
                        ea.Vh[(long)b * (256 * SEQP) + (long)c * SEQP + s] = f2bf(v);
                    }
                } else {  // EPI_FINAL
                    int nimg = m / 49, p = m % 49;
                    long xi = (long)nimg * (2048 * 49) + (long)n * 49 + p;
                    float xv = ea.x[xi];
                    float g = ea.gamma[0];
                    ea.fout[xi] = (g * v + xv) * v + xv;
                }
            }
}

// [32][2048][49] f32 -> token-major bf16 planes. z=0: x -> Xt hi+lo; z=1: domainX -> DXt hi.
__global__ __launch_bounds__(256)
void transpose_split(const float* __restrict__ x, const float* __restrict__ dX,
                     ushort* __restrict__ Xth, ushort* __restrict__ Xtl,
                     ushort* __restrict__ DXth)
{
    __shared__ float tile[64][50];
    int n = blockIdx.x, c0 = blockIdx.y * 64;
    const float* src = blockIdx.z ? dX : x;
    const float* s = src + (long)n * (2048 * 49) + (long)c0 * 49;
    for (int idx = threadIdx.x; idx < 64 * 49; idx += 256)
        tile[idx / 49][idx % 49] = s[idx];
    __syncthreads();
    for (int idx = threadIdx.x; idx < 49 * 64; idx += 256) {
        int p = idx >> 6, cl = idx & 63;
        float v = tile[cl][p];
        long o = (long)(n * 49 + p) * 2048 + c0 + cl;
        if (blockIdx.z) { DXth[o] = f2bf(v); }
        else { ushort h, l; split2(v, h, l); Xth[o] = h; Xtl[o] = l; }
    }
}

// Weight bf16 conversion + concatenation + bias concats.
__global__ __launch_bounds__(256)
void split_weights(const float* c11, const float* c21, const float* conv3,
                   const float* wval, const float* l2d, const float* l2dY,
                   const float* l2u, const float* l2uY,
                   const float* c22, const float* c12,
                   const float* b_c11, const float* b_c21, const float* b_conv3,
                   const float* b_c22, const float* b_c12,
                   const float* b_l2u, const float* b_l2uY,
                   ushort* Wg1h, ushort* Wg1l, ushort* Wvalh, ushort* Wg4h,
                   ushort* Wg56h, ushort* Wg7h,
                   float* bg1, float* bg7, float* bg56)
{
    int e = blockIdx.x * 256 + threadIdx.x;
    if (e < 1048576) {          // Wg1 = [c11 | c21 | conv3], split hi+lo
        float v = e < 262144 ? c11[e] : e < 524288 ? c21[e - 262144] : conv3[e - 524288];
        ushort h, l; split2(v, h, l); Wg1h[e] = h; Wg1l[e] = l;
    } else if (e < 1572864) { Wvalh[e - 1048576] = f2bf(wval[e - 1048576]); }
    else if (e < 2621440) { int i = e - 1572864; Wg4h[i]  = f2bf(i < 524288 ? l2d[i] : l2dY[i - 524288]); }
    else if (e < 3670016) { int i = e - 2621440; Wg56h[i] = f2bf(i < 524288 ? l2u[i] : l2uY[i - 524288]); }
    else if (e < 4194304) { int i = e - 3670016; Wg7h[i]  = f2bf(i < 262144 ? c22[i] : c12[i - 262144]); }
    else if (e < 4194816) { int i = e - 4194304; bg1[i] = i < 128 ? b_c11[i] : i < 256 ? b_c21[i - 128] : b_conv3[i - 256]; }
    else if (e < 4195072) { int i = e - 4194816; bg7[i] = i < 128 ? b_c22[i] : b_c12[i - 128]; }
    else if (e < 4199168) { int i = e - 4195072; bg56[i] = i < 2048 ? b_l2u[i] : b_l2uY[i - 2048]; }
}

// cX[o] = w_value[o]·b_l1down + b_l1up  (and _Y)
__global__ __launch_bounds__(256)
void prep_c(const float* __restrict__ w_value,
            const float* __restrict__ bdX, const float* __restrict__ buX,
            const float* __restrict__ bdY, const float* __restrict__ buY,
            float* __restrict__ cX, float* __restrict__ cY)
{
    int o = blockIdx.x * 256 + threadIdx.x;
    const float* bd = blockIdx.y ? bdY : bdX;
    const float* bu = blockIdx.y ? buY : buX;
    float* outp     = blockIdx.y ? cY : cX;
    float acc = 0.f;
    const float* wrow = w_value + (long)o * 256;
    for (int c = 0; c < 256; ++c) acc = fmaf(wrow[c], bd[c], acc);
    outp[o] = acc + bu[o];
}

// e[j] = w_l2down[j]·cX + b_l2down[j]  (wave per j); writes into bg4 / bg4+256
__global__ __launch_bounds__(256)
void prep_e(const float* __restrict__ WX, const float* __restrict__ bX,
            const float* __restrict__ cX,
            const float* __restrict__ WY, const float* __restrict__ bY,
            const float* __restrict__ cY,
            float* __restrict__ eX, float* __restrict__ eY)
{
    const float* W = blockIdx.y ? WY : WX;
    const float* b = blockIdx.y ? bY : bX;
    const float* c = blockIdx.y ? cY : cX;
    float* e       = blockIdx.y ? eY : eX;
    int wave = threadIdx.x >> 6, lane = threadIdx.x & 63;
    int j = blockIdx.x * 4 + wave;
    float acc = 0.f;
    const float* wrow = W + (long)j * 2048;
    for (int o = lane; o < 2048; o += 64) acc = fmaf(wrow[o], c[o], acc);
    for (int off = 32; off; off >>= 1) acc += __shfl_down(acc, off, 64);
    if (lane == 0) e[j] = acc + b[j];
}

// KmT[b][m][ci] gather from Kt[t][c], both planes
__global__ __launch_bounds__(256)
void permute_k2(const ushort* __restrict__ KtH, const ushort* __restrict__ KtL,
                ushort* __restrict__ KmH, ushort* __restrict__ KmL)
{
    int idx = blockIdx.x * 256 + threadIdx.x;      // 4*392*256
    int b  = idx / 100352;
    int rr = idx % 100352;
    int mm = rr >> 8, ci = rr & 255;
    int flat = ci * 392 + mm;
    int wd = flat / 14336;
    int f  = (flat / 1792) & 7;
    int hd = (flat / 256) % 7;
    int c  = flat & 255;
    int p  = wd * 7 + hd;
    long t = (long)((b * 8 + f) * 49 + p);
    KmH[idx] = KtH[t * 256 + c];
    KmL[idx] = KtL[t * 256 + c];
}

// Row softmax over f32 logits [row][416] (valid 392), bf16 out with zeroed pad.
__global__ __launch_bounds__(64)
void softmax_bf16(const float* __restrict__ L, ushort* __restrict__ attn)
{
    int row = blockIdx.x;
    const float* rp = L + (long)row * SEQP;
    ushort* op = attn + (long)row * SEQP;
    int lane = threadIdx.x;
    float v[7]; float mx = -1e30f;
#pragma unroll
    for (int i = 0; i < 7; ++i) {
        int idx = lane + i * 64;
        v[i] = (idx < 392) ? rp[idx] : -1e30f;
        mx = fmaxf(mx, v[i]);
    }
    for (int off = 32; off; off >>= 1) mx = fmaxf(mx, __shfl_xor(mx, off, 64));
    float s = 0.f;
#pragma unroll
    for (int i = 0; i < 7; ++i) { v[i] = __expf(v[i] - mx); s += v[i]; }
    for (int off = 32; off; off >>= 1) s += __shfl_xor(s, off, 64);
    float inv = 1.f / s;
#pragma unroll
    for (int i = 0; i < 7; ++i) {
        int idx = lane + i * 64;
        if (idx < 392) op[idx] = f2bf(v[i] * inv);
        else if (idx < SEQP) op[idx] = 0;
    }
}

extern "C" void kernel_launch(void* const* d_in, const int* in_sizes, int n_in,
                              void* d_out, int out_size, void* d_ws, size_t ws_size,
                              hipStream_t stream)
{
    const float* x        = (const float*)d_in[0];
    const float* domainX  = (const float*)d_in[1];
    const float* w_conv3  = (const float*)d_in[5];
    const float* b_conv3  = (const float*)d_in[6];
    const float* w_value  = (const float*)d_in[7];
    const float* b_value  = (const float*)d_in[8];
    const float* b_l1down   = (const float*)d_in[9];
    const float* b_l1up     = (const float*)d_in[10];
    const float* b_l1down_Y = (const float*)d_in[11];
    const float* b_l1up_Y   = (const float*)d_in[12];
    const float* w_l2down   = (const float*)d_in[13];
    const float* b_l2down   = (const float*)d_in[14];
    const float* w_l2up     = (const float*)d_in[15];
    const float* b_l2up     = (const float*)d_in[16];
    const float* w_l2down_Y = (const float*)d_in[17];
    const float* b_l2down_Y = (const float*)d_in[18];
    const float* w_l2up_Y   = (const float*)d_in[19];
    const float* b_l2up_Y   = (const float*)d_in[20];
    const float* w_c11 = (const float*)d_in[21];
    const float* b_c11 = (const float*)d_in[22];
    const float* w_c12 = (const float*)d_in[23];
    const float* b_c12 = (const float*)d_in[24];
    const float* w_c21 = (const float*)d_in[25];
    const float* b_c21 = (const float*)d_in[26];
    const float* w_c22 = (const float*)d_in[27];
    const float* b_c22 = (const float*)d_in[28];
    const float* pos   = (const float*)d_in[29];
    const float* gamma = (const float*)d_in[30];
    float* out = (float*)d_out;

    ushort* U = (ushort*)d_ws;
    float*  Fp = (float*)d_ws;

    // ushort offsets (elements)
    const long oXt_h   = 0;                 // [1568][2048]; reused (with Xt_l) as dXdY
    const long oXt_l   = 3211264;
    const long oDXt_h  = 6422528;           // reused as U0
    const long oWg1_h  = 9633792;           // [512][2048] c11|c21|conv3
    const long oWg1_l  = 10682368;
    const long oWval_h = 11730944;          // [2048][256]
    const long oWg4_h  = 12255232;          // [512][2048] l2down|l2down_Y
    const long oWg56_h = 13303808;          // [2][2048][256] l2up|l2up_Y
    const long oWg7_h  = 14352384;          // [2][128][2048] c22|c12
    const long oP0_h   = 14876672;          // [1568][256]
    const long oD14_h  = 15278080;          // [1568][512]
    const long oQKt_h  = 16080896;          // Q[1568][256] then Kt[1568][256]
    const long oQKt_l  = 16883712;
    const long oKmT_h  = 17686528;          // [4][392][256]
    const long oKmT_l  = 18087936;
    const long oVT_h   = 18489344;          // [4][256][416]
    const long oattn_h = 18915328;          // [4][392][416]
    const long oO_h    = 19567616;          // [1568][256]
    const long oU0_h   = oDXt_h;
    const long odXdY_h = oXt_h;             // [2][1568][2048]
    // float offsets
    const long fL    = 9984512;             // [4][392][416]
    const long fcX   = 10636800;
    const long fcY   = 10638848;
    const long fbg1  = 10640896;            // 512
    const long fbg4  = 10641408;            // 512 (eX|eY)
    const long fbg56 = 10641920;            // 4096
    const long fbg7  = 10646016;            // 256

    EpiArgs Z = {};

    // 0. zero VT (pad cols must be 0 for the K=416 PV GEMM)
    hipMemsetAsync(U + oVT_h, 0, 425984 * sizeof(ushort), stream);

    // 1. weights -> bf16 (+ concats, bias concats)
    split_weights<<<dim3(16403), 256, 0, stream>>>(
        w_c11, w_c21, w_conv3, w_value, w_l2down, w_l2down_Y, w_l2up, w_l2up_Y,
        w_c22, w_c12, b_c11, b_c21, b_conv3, b_c22, b_c12, b_l2up, b_l2up_Y,
        U + oWg1_h, U + oWg1_l, U + oWval_h, U + oWg4_h, U + oWg56_h, U + oWg7_h,
        Fp + fbg1, Fp + fbg7, Fp + fbg56);

    // 2. x -> Xt hi/lo ; domainX -> DXt hi
    transpose_split<<<dim3(32, 32, 2), 256, 0, stream>>>(
        x, domainX, U + oXt_h, U + oXt_l, U + oDXt_h);

    // 3. folded layer-1 bias constants
    prep_c<<<dim3(8, 2), 256, 0, stream>>>(w_value, b_l1down, b_l1up,
                                           b_l1down_Y, b_l1up_Y, Fp + fcX, Fp + fcY);
    // 4. folded layer-2 down biases -> bg4 = [eX | eY]
    prep_e<<<dim3(64, 2), 256, 0, stream>>>(w_l2down, b_l2down, Fp + fcX,
                                            w_l2down_Y, b_l2down_Y, Fp + fcY,
                                            Fp + fbg4, Fp + fbg4 + 256);

    // 5. G2: P0 = DXt @ conv3^T        [1568][256], K=2048 (plain)
    { EpiArgs ea = Z; ea.Ch = U + oP0_h;
      mgemm<EPI_BF16, false><<<dim3(4, 25, 1), 256, 0, stream>>>(
        U + oDXt_h, nullptr, 2048, 0, U + oWg1_h + 524288, nullptr, 2048, 0,
        nullptr, 0, 256, 0, TOKENS, 256, 2048, ea); }

    // 6. G1: Xt @ [c11|c21|conv3]^T -> Q1/K1 (split) + VT (bf16, +pos)  (3-pass)
    { EpiArgs ea = Z; ea.Ch = U + oQKt_h; ea.Cl = U + oQKt_l;
      ea.Kh = U + oQKt_h + 401408; ea.Kl = U + oQKt_l + 401408;
      ea.Vh = U + oVT_h; ea.pos = pos;
      mgemm<EPI_G1, true><<<dim3(8, 25, 1), 256, 0, stream>>>(
        U + oXt_h, U + oXt_l, 2048, 0, U + oWg1_h, U + oWg1_l, 2048, 0,
        Fp + fbg1, 0, 0, 0, TOKENS, 512, 2048, ea); }

    // 7. G3: U0 = P0 @ w_value^T       [1568][2048], K=256 (plain)
    { EpiArgs ea = Z; ea.Ch = U + oU0_h;
      mgemm<EPI_BF16, false><<<dim3(32, 25, 1), 256, 0, stream>>>(
        U + oP0_h, nullptr, 256, 0, U + oWval_h, nullptr, 256, 0,
        nullptr, 0, 2048, 0, TOKENS, 2048, 256, ea); }

    // 8. G4: D14 = U0 @ [l2down|l2down_Y]^T + [eX|eY]   [1568][512], K=2048
    { EpiArgs ea = Z; ea.Ch = U + oD14_h;
      mgemm<EPI_BF16, false><<<dim3(8, 25, 1), 256, 0, stream>>>(
        U + oU0_h, nullptr, 2048, 0, U + oWg4_h, nullptr, 2048, 0,
        Fp + fbg4, 0, 512, 0, TOKENS, 512, 2048, ea); }

    // 9. G56: dXdY[z] = D14[:, z*256:] @ l2up(_Y)^T + b   [2][1568][2048], K=256
    { EpiArgs ea = Z; ea.Ch = U + odXdY_h;
      mgemm<EPI_BF16, false><<<dim3(32, 25, 2), 256, 0, stream>>>(
        U + oD14_h, nullptr, 512, 256, U + oWg56_h, nullptr, 256, 524288,
        Fp + fbg56, 2048, 2048, (long)TOKENS * 2048, TOKENS, 2048, 256, ea); }

    // 10. G7: z=0: K2 = dX@c22 ; z=1: Q2 = dY@c12  (split out, signed stride)
    { EpiArgs ea = Z; ea.Ch = U + oQKt_h + 401408 + 128; ea.Cl = U + oQKt_l + 401408 + 128;
      mgemm<EPI_SPLIT, false><<<dim3(2, 25, 2), 256, 0, stream>>>(
        U + odXdY_h, nullptr, 2048, (long)TOKENS * 2048, U + oWg7_h, nullptr, 2048, 262144,
        Fp + fbg7, 128, 256, -401408L, TOKENS, 128, 2048, ea); }

    // 11. K permute gather (both planes)
    permute_k2<<<dim3(1568), 256, 0, stream>>>(
        U + oQKt_h + 401408, U + oQKt_l + 401408, U + oKmT_h, U + oKmT_l);

    // 12. logits L[b] = Q[b] @ KmT[b]^T   f32 out (3-pass split)
    { EpiArgs ea = Z; ea.Cf = Fp + fL;
      mgemm<EPI_F32, true><<<dim3(7, 7, 4), 256, 0, stream>>>(
        U + oQKt_h, U + oQKt_l, 256, 100352, U + oKmT_h, U + oKmT_l, 256, 100352,
        nullptr, 0, SEQP, (long)392 * SEQP, 392, 392, 256, ea); }

    // 13. softmax -> bf16 probs (pad zeroed)
    softmax_bf16<<<dim3(1568), 64, 0, stream>>>(Fp + fL, U + oattn_h);

    // 14. PV: O[b] = attn[b] @ VT[b]^T   [392][256], K=416 (plain)
    { EpiArgs ea = Z; ea.Ch = U + oO_h;
      mgemm<EPI_BF16, false><<<dim3(4, 7, 4), 256, 0, stream>>>(
        U + oattn_h, nullptr, SEQP, (long)392 * SEQP, U + oVT_h, nullptr, SEQP, (long)256 * SEQP,
        nullptr, 0, 256, (long)392 * 256, 392, 256, SEQP, ea); }

    // 15. final: z = O @ w_value^T + b_value ; out = (g*z + x)*z + x
    { EpiArgs ea = Z; ea.x = x; ea.gamma = gamma; ea.fout = out;
      mgemm<EPI_FINAL, false><<<dim3(32, 25, 1), 256, 0, stream>>>(
        U + oO_h, nullptr, 256, 0, U + oWval_h, nullptr, 256, 0,
        b_value, 0, 0, 0, TOKENS, 2048, 256, ea); }
}

// Round 3
// 210.812 us; speedup vs baseline: 10.4759x; 1.0777x over previous
//
#include <hip/hip_runtime.h>
#include <hip/hip_bf16.h>

// ---------------------------------------------------------------------------
// SCSAttention on MI355X. All GEMMs via mfma_f32_16x16x32_bf16, 64x128 tiles,
// global_load_lds width-16 staging with XOR k-chunk swizzle, split-K with f32
// partials for parallelism-starved shapes. Q/K/logits path = bf16x2 3-pass.
// ---------------------------------------------------------------------------

typedef __attribute__((ext_vector_type(8))) short short8;
typedef __attribute__((ext_vector_type(4))) float f32x4;

#define TOKENS 1568
#define SEQP   416

__device__ __forceinline__ ushort f2bf(float f) {
    uint32_t u = __float_as_uint(f);
    u += 0x7fffu + ((u >> 16) & 1u);   // RNE
    return (ushort)(u >> 16);
}
__device__ __forceinline__ float bf2f(ushort h) { return __uint_as_float(((uint32_t)h) << 16); }
__device__ __forceinline__ void split2(float v, ushort& h, ushort& l) {
    h = f2bf(v); l = f2bf(v - bf2f(h));
}

__device__ __forceinline__ void gl16(const void* g, void* l) {
    __builtin_amdgcn_global_load_lds(
        (const __attribute__((address_space(1))) unsigned int*)g,
        (__attribute__((address_space(3))) unsigned int*)l, 16, 0, 0);
}

#define EPI_PART  0
#define EPI_BF16  1
#define EPI_FINAL 2

// C[m][n] = sum_k A[m][k]*W[n][k]; tile 64(M)x128(N), BK=32, 4 waves (2x2),
// wave = 32x64 = 2x4 16x16 frags. SPLIT: 3-pass bf16x2 (hi/lo planes).
template<int EPI, bool SPLIT>
__global__ __launch_bounds__(256)
void gmm(const ushort* __restrict__ Ah, const ushort* __restrict__ Al, int lda, long sA,
         const ushort* __restrict__ Wh, const ushort* __restrict__ Wl, int ldw, long sW,
         const float* __restrict__ bias, int sB,
         int nkc, int Kc,
         float* __restrict__ fO, ushort* __restrict__ bO,
         int ldc, long sC, int M, int N,
         const float* __restrict__ ex, const float* __restrict__ gamma,
         float* __restrict__ fout)
{
    __shared__ __align__(16) ushort sA_h[64 * 32], sW_h[128 * 32];
    __shared__ __align__(16) ushort sA_l[SPLIT ? 64 * 32 : 8], sW_l[SPLIT ? 128 * 32 : 8];

    const int tid = threadIdx.x;
    const int bz = blockIdx.z / nkc;
    const int kc = blockIdx.z % nkc;
    const int row0 = blockIdx.y * 64, col0 = blockIdx.x * 128;

    // ---- staging addresses (lane supplies one 16B chunk per call) ----
    const int srow = tid >> 2;                       // 0..63
    const int sq   = (tid & 3) ^ (srow & 3);         // swizzled source k-chunk
    int am  = row0 + srow;      if (am  > M - 1) am  = M - 1;
    int wn0 = col0 + srow;      if (wn0 > N - 1) wn0 = N - 1;
    int wn1 = col0 + 64 + srow; if (wn1 > N - 1) wn1 = N - 1;
    const long kbase = (long)kc * Kc + sq * 8;
    const ushort* gA  = Ah + bz * sA + (long)am  * lda + kbase;
    const ushort* gW0 = Wh + bz * sW + (long)wn0 * ldw + kbase;
    const ushort* gW1 = Wh + bz * sW + (long)wn1 * ldw + kbase;
    const ushort *gAl = nullptr, *gWl0 = nullptr, *gWl1 = nullptr;
    if constexpr (SPLIT) {
        gAl  = Al + bz * sA + (long)am  * lda + kbase;
        gWl0 = Wl + bz * sW + (long)wn0 * ldw + kbase;
        gWl1 = Wl + bz * sW + (long)wn1 * ldw + kbase;
    }
    const int wb = (tid & 192) * 8;                  // wave-uniform LDS chunk base

    // ---- fragment read offsets (swizzled) ----
    const int lane = tid & 63, wv = tid >> 6;
    const int wr = (wv >> 1) * 32, wc = (wv & 1) * 64;
    const int fr = lane & 15;
    const int ksw = ((lane >> 4) ^ (lane & 3)) * 8;
    int aoff[2], boff[4];
#pragma unroll
    for (int mi = 0; mi < 2; ++mi) aoff[mi] = (wr + mi * 16 + fr) * 32 + ksw;
#pragma unroll
    for (int ni = 0; ni < 4; ++ni) boff[ni] = (wc + ni * 16 + fr) * 32 + ksw;

    f32x4 acc[2][4];
#pragma unroll
    for (int mi = 0; mi < 2; ++mi)
#pragma unroll
        for (int ni = 0; ni < 4; ++ni) acc[mi][ni] = (f32x4){0.f, 0.f, 0.f, 0.f};

    for (int k0 = 0; k0 < Kc; k0 += 32) {
        __syncthreads();
        gl16(gA + k0, sA_h + wb);
        gl16(gW0 + k0, sW_h + wb);
        gl16(gW1 + k0, sW_h + 2048 + wb);
        if constexpr (SPLIT) {
            gl16(gAl + k0, sA_l + wb);
            gl16(gWl0 + k0, sW_l + wb);
            gl16(gWl1 + k0, sW_l + 2048 + wb);
        }
        __syncthreads();   // compiler drains vmcnt before barrier

        short8 fa[2], fb[4];
#pragma unroll
        for (int mi = 0; mi < 2; ++mi) fa[mi] = *(const short8*)&sA_h[aoff[mi]];
#pragma unroll
        for (int ni = 0; ni < 4; ++ni) fb[ni] = *(const short8*)&sW_h[boff[ni]];
#pragma unroll
        for (int mi = 0; mi < 2; ++mi)
#pragma unroll
            for (int ni = 0; ni < 4; ++ni)
                acc[mi][ni] = __builtin_amdgcn_mfma_f32_16x16x32_bf16(fa[mi], fb[ni], acc[mi][ni], 0, 0, 0);
        if constexpr (SPLIT) {
            short8 ga[2], gb[4];
#pragma unroll
            for (int mi = 0; mi < 2; ++mi) ga[mi] = *(const short8*)&sA_l[aoff[mi]];
#pragma unroll
            for (int ni = 0; ni < 4; ++ni) gb[ni] = *(const short8*)&sW_l[boff[ni]];
#pragma unroll
            for (int mi = 0; mi < 2; ++mi)
#pragma unroll
                for (int ni = 0; ni < 4; ++ni) {
                    acc[mi][ni] = __builtin_amdgcn_mfma_f32_16x16x32_bf16(fa[mi], gb[ni], acc[mi][ni], 0, 0, 0);
                    acc[mi][ni] = __builtin_amdgcn_mfma_f32_16x16x32_bf16(ga[mi], fb[ni], acc[mi][ni], 0, 0, 0);
                }
        }
    }

    const int q4 = (lane >> 4) * 4;
    float g = 0.f;
    if constexpr (EPI == EPI_FINAL) g = gamma[0];
#pragma unroll
    for (int mi = 0; mi < 2; ++mi)
#pragma unroll
        for (int ni = 0; ni < 4; ++ni)
#pragma unroll
            for (int qi = 0; qi < 4; ++qi) {
                int m = row0 + wr + mi * 16 + q4 + qi;
                int n = col0 + wc + ni * 16 + fr;
                if (m >= M || n >= N) continue;
                float v = acc[mi][ni][qi];
                if (bias) v += bias[bz * sB + n];
                if constexpr (EPI == EPI_PART) {
                    fO[(long)blockIdx.z * sC + (long)m * ldc + n] = v;
                } else if constexpr (EPI == EPI_BF16) {
                    bO[(long)blockIdx.z * sC + (long)m * ldc + n] = f2bf(v);
                } else {
                    int nimg = m / 49, p = m % 49;
                    long xi = (long)nimg * (2048 * 49) + (long)n * 49 + p;
                    float xv = ex[xi];
                    fout[xi] = (g * v + xv) * v + xv;
                }
            }
}

// [32][2048][49] f32 -> token-major bf16. z=0: x -> Xt hi+lo; z=1: domainX -> DXt hi.
__global__ __launch_bounds__(256)
void transpose_split(const float* __restrict__ x, const float* __restrict__ dX,
                     ushort* __restrict__ Xth, ushort* __restrict__ Xtl,
                     ushort* __restrict__ DXth)
{
    __shared__ float tile[64][50];
    int n = blockIdx.x, c0 = blockIdx.y * 64;
    const float* src = blockIdx.z ? dX : x;
    const float* s = src + (long)n * (2048 * 49) + (long)c0 * 49;
    for (int idx = threadIdx.x; idx < 64 * 49; idx += 256)
        tile[idx / 49][idx % 49] = s[idx];
    __syncthreads();
    for (int idx = threadIdx.x; idx < 49 * 64; idx += 256) {
        int p = idx >> 6, cl = idx & 63;
        float v = tile[cl][p];
        long o = (long)(n * 49 + p) * 2048 + c0 + cl;
        if (blockIdx.z) { DXth[o] = f2bf(v); }
        else { ushort h, l; split2(v, h, l); Xth[o] = h; Xtl[o] = l; }
    }
}

// Weights needed by G1/G2: Wg1 = [c11|c21|conv3] hi+lo, bg1 concat.
__global__ __launch_bounds__(256)
void sw_A(const float* c11, const float* c21, const float* conv3,
          const float* b_c11, const float* b_c21, const float* b_conv3,
          ushort* Wh, ushort* Wl, float* bg1)
{
    int e = blockIdx.x * 256 + threadIdx.x;
    if (e < 1048576) {
        float v = e < 262144 ? c11[e] : e < 524288 ? c21[e - 262144] : conv3[e - 524288];
        ushort h, l; split2(v, h, l); Wh[e] = h; Wl[e] = l;
    } else if (e < 1049088) {
        int i = e - 1048576;
        bg1[i] = i < 128 ? b_c11[i] : i < 256 ? b_c21[i - 128] : b_conv3[i - 256];
    }
}

// Remaining weights (written after G2; they overlay dead Xt/Wg1 space).
__global__ __launch_bounds__(256)
void sw_B(const float* wval, const float* l2d, const float* l2dY,
          const float* l2u, const float* l2uY, const float* c22, const float* c12,
          const float* b_l2u, const float* b_l2uY, const float* b_c22, const float* b_c12,
          ushort* Wval, ushort* Wg4, ushort* Wg56, ushort* Wg7,
          float* bg56, float* bg7)
{
    int e = blockIdx.x * 256 + threadIdx.x;
    if (e < 524288) { Wval[e] = f2bf(wval[e]); }
    else if (e < 1572864) { int i = e - 524288;  Wg4[i]  = f2bf(i < 524288 ? l2d[i] : l2dY[i - 524288]); }
    else if (e < 2621440) { int i = e - 1572864; Wg56[i] = f2bf(i < 524288 ? l2u[i] : l2uY[i - 524288]); }
    else if (e < 3145728) { int i = e - 2621440; Wg7[i]  = f2bf(i < 262144 ? c22[i] : c12[i - 262144]); }
    else if (e < 3149824) { int i = e - 3145728; bg56[i] = i < 2048 ? b_l2u[i] : b_l2uY[i - 2048]; }
    else if (e < 3150080) { int i = e - 3149824; bg7[i]  = i < 128 ? b_c22[i] : b_c12[i - 128]; }
}

// cX[o] = w_value[o]·b_l1down + b_l1up (and _Y)
__global__ __launch_bounds__(256)
void prep_c(const float* __restrict__ w_value,
            const float* __restrict__ bdX, const float* __restrict__ buX,
            const float* __restrict__ bdY, const float* __restrict__ buY,
            float* __restrict__ cX, float* __restrict__ cY)
{
    int o = blockIdx.x * 256 + threadIdx.x;
    const float* bd = blockIdx.y ? bdY : bdX;
    const float* bu = blockIdx.y ? buY : buX;
    float* outp     = blockIdx.y ? cY : cX;
    float acc = 0.f;
    const float* wrow = w_value + (long)o * 256;
    for (int c = 0; c < 256; ++c) acc = fmaf(wrow[c], bd[c], acc);
    outp[o] = acc + bu[o];
}

// e[j] = w_l2down[j]·c + b_l2down[j]  (wave per j)
__global__ __launch_bounds__(256)
void prep_e(const float* __restrict__ WX, const float* __restrict__ bX,
            const float* __restrict__ cX,
            const float* __restrict__ WY, const float* __restrict__ bY,
            const float* __restrict__ cY,
            float* __restrict__ eX, float* __restrict__ eY)
{
    const float* W = blockIdx.y ? WY : WX;
    const float* b = blockIdx.y ? bY : bX;
    const float* c = blockIdx.y ? cY : cX;
    float* e       = blockIdx.y ? eY : eX;
    int wave = threadIdx.x >> 6, lane = threadIdx.x & 63;
    int j = blockIdx.x * 4 + wave;
    float acc = 0.f;
    const float* wrow = W + (long)j * 2048;
    for (int o = lane; o < 2048; o += 64) acc = fmaf(wrow[o], c[o], acc);
    for (int off = 32; off; off >>= 1) acc += __shfl_down(acc, off, 64);
    if (lane == 0) e[j] = acc + b[j];
}

// G1 reduce: 8 K-chunks + bias -> Q split / K split / V bf16 (+pos, transposed, pad-zeroed)
__global__ __launch_bounds__(256)
void r_g1(const float* __restrict__ P, const float* __restrict__ bg1,
          const float* __restrict__ pos,
          ushort* Qh, ushort* Ql, ushort* Kh, ushort* Kl, ushort* Vh)
{
    int idx = blockIdx.x * 256 + threadIdx.x;      // 1568*512
    int m = idx >> 9, n = idx & 511;
    float v = 0.f;
#pragma unroll
    for (int kc = 0; kc < 8; ++kc) v += P[kc * 802816 + idx];
    v += bg1[n];
    if (n < 128) { ushort h, l; split2(v, h, l); Qh[m * 256 + n] = h; Ql[m * 256 + n] = l; }
    else if (n < 256) { ushort h, l; split2(v, h, l); Kh[m * 256 + n - 128] = h; Kl[m * 256 + n - 128] = l; }
    else {
        int c = n - 256, f = (m / 49) & 7, p = m % 49;
        v += pos[f * 12544 + c * 49 + p];
        int b = m / 392, s = m % 392;
        long o = (long)b * 106496 + (long)c * 416 + s;
        Vh[o] = f2bf(v);
        if (s < 24) Vh[o - s + 392 + s] = 0;      // zero the K-pad columns
    }
}

__global__ __launch_bounds__(256)
void r_g2(const float* __restrict__ P, ushort* __restrict__ P0)
{
    int idx = blockIdx.x * 256 + threadIdx.x;      // 1568*256
    float v = P[idx] + P[401408 + idx] + P[802816 + idx] + P[1204224 + idx];
    P0[idx] = f2bf(v);
}

__global__ __launch_bounds__(256)
void r_g4(const float* __restrict__ P, const float* __restrict__ bg4,
          ushort* __restrict__ D14)
{
    int idx = blockIdx.x * 256 + threadIdx.x;      // 1568*512
    float v = P[idx] + P[802816 + idx] + P[1605632 + idx] + P[2408448 + idx] + bg4[idx & 511];
    D14[idx] = f2bf(v);
}

// G7 reduce: [bz][kc][1568][128]; bz=0 -> K cols 128+, bz=1 -> Q cols 128+
__global__ __launch_bounds__(256)
void r_g7(const float* __restrict__ P, const float* __restrict__ bg7,
          ushort* Kh, ushort* Kl, ushort* Qh, ushort* Ql)
{
    int idx = blockIdx.x * 256 + threadIdx.x;      // 2*1568*128
    int bz = idx / 200704, r = idx % 200704;
    int m = r >> 7, n = r & 127;
    const float* p = P + (long)bz * 802816;
    float v = p[r] + p[200704 + r] + p[401408 + r] + p[602112 + r] + bg7[bz * 128 + n];
    ushort h, l; split2(v, h, l);
    long o = (long)m * 256 + 128 + n;
    if (bz == 0) { Kh[o] = h; Kl[o] = l; } else { Qh[o] = h; Ql[o] = l; }
}

// KmT[b][m][ci] gather from Kt[t][c], both planes
__global__ __launch_bounds__(256)
void permute_k2(const ushort* __restrict__ KtH, const ushort* __restrict__ KtL,
                ushort* __restrict__ KmH, ushort* __restrict__ KmL)
{
    int idx = blockIdx.x * 256 + threadIdx.x;      // 4*392*256
    int b = idx / 100352, rr = idx % 100352;
    int mm = rr >> 8, ci = rr & 255;
    int flat = ci * 392 + mm;
    int wd = flat / 14336;
    int f  = (flat / 1792) & 7;
    int hd = (flat / 256) % 7;
    int c  = flat & 255;
    int p  = wd * 7 + hd;
    long t = (long)((b * 8 + f) * 49 + p);
    KmH[idx] = KtH[t * 256 + c];
    KmL[idx] = KtL[t * 256 + c];
}

// softmax over summed logit partials [b][kc][392][416] -> bf16 attn (pad zeroed)
__global__ __launch_bounds__(64)
void softmax_bf16(const float* __restrict__ P, ushort* __restrict__ attn)
{
    int row = blockIdx.x;                           // 1568
    int b = row / 392, mm = row % 392;
    const float* r0 = P + (long)(b * 2) * 163072 + (long)mm * 416;
    const float* r1 = r0 + 163072;
    ushort* op = attn + (long)row * 416;
    int lane = threadIdx.x;
    float v[7]; float mx = -1e30f;
#pragma unroll
    for (int i = 0; i < 7; ++i) {
        int idx = lane + i * 64;
        v[i] = (idx < 392) ? (r0[idx] + r1[idx]) : -1e30f;
        mx = fmaxf(mx, v[i]);
    }
    for (int off = 32; off; off >>= 1) mx = fmaxf(mx, __shfl_xor(mx, off, 64));
    float s = 0.f;
#pragma unroll
    for (int i = 0; i < 7; ++i) { v[i] = __expf(v[i] - mx); s += v[i]; }
    for (int off = 32; off; off >>= 1) s += __shfl_xor(s, off, 64);
    float inv = 1.f / s;
#pragma unroll
    for (int i = 0; i < 7; ++i) {
        int idx = lane + i * 64;
        if (idx < 392) op[idx] = f2bf(v[i] * inv);
        else if (idx < 416) op[idx] = 0;
    }
}

extern "C" void kernel_launch(void* const* d_in, const int* in_sizes, int n_in,
                              void* d_out, int out_size, void* d_ws, size_t ws_size,
                              hipStream_t stream)
{
    const float* x        = (const float*)d_in[0];
    const float* domainX  = (const float*)d_in[1];
    const float* w_conv3  = (const float*)d_in[5];
    const float* b_conv3  = (const float*)d_in[6];
    const float* w_value  = (const float*)d_in[7];
    const float* b_value  = (const float*)d_in[8];
    const float* b_l1down   = (const float*)d_in[9];
    const float* b_l1up     = (const float*)d_in[10];
    const float* b_l1down_Y = (const float*)d_in[11];
    const float* b_l1up_Y   = (const float*)d_in[12];
    const float* w_l2down   = (const float*)d_in[13];
    const float* b_l2down   = (const float*)d_in[14];
    const float* w_l2up     = (const float*)d_in[15];
    const float* b_l2up     = (const float*)d_in[16];
    const float* w_l2down_Y = (const float*)d_in[17];
    const float* b_l2down_Y = (const float*)d_in[18];
    const float* w_l2up_Y   = (const float*)d_in[19];
    const float* b_l2up_Y   = (const float*)d_in[20];
    const float* w_c11 = (const float*)d_in[21];
    const float* b_c11 = (const float*)d_in[22];
    const float* w_c12 = (const float*)d_in[23];
    const float* b_c12 = (const float*)d_in[24];
    const float* w_c21 = (const float*)d_in[25];
    const float* b_c21 = (const float*)d_in[26];
    const float* w_c22 = (const float*)d_in[27];
    const float* b_c22 = (const float*)d_in[28];
    const float* pos   = (const float*)d_in[29];
    const float* gamma = (const float*)d_in[30];
    float* out = (float*)d_out;

    ushort* U = (ushort*)d_ws;
    float*  Fp = (float*)d_ws;

    // ---- workspace layout (liveness-overlapped; total 49.19 MB) ----
    // ushort offsets
    const long oQKt_h = 12845056;   // LateZone (valid after G1; overlays dead Xt/Wg1)
    const long oQKt_l = 13647872;
    const long oVT    = 14450688;   // [4][256][416]
    const long oKmT_h = 14876672;
    const long oKmT_l = 15278080;
    const long oattn  = 15679488;   // [4][392][416]
    const long oO     = 16331776;
    const long oP0    = 16733184;
    const long oD14   = 17134592;   // [1568][512]
    const long oWval  = 17937408;
    const long oWg4   = 18461696;
    const long oWg56  = 19510272;
    const long oWg7   = 20558848;
    const long oXt_h  = 12845056;   // EarlyZone (dead after G1) — same bytes as LateZone
    const long oXt_l  = 16056320;
    const long oWg1_h = 19267584;
    const long oWg1_l = 20316160;
    const long oDXt   = 21364736;   // -> U0 after G3
    const long odXdY  = 0;          // [2][1568][2048] (after partials die)
    // f32 offsets
    const long fpG7  = 3211264;     // G7 partials (bytes 12.85-19.27 MB)
    const long fcX   = 12288000;
    const long fcY   = 12290048;
    const long fbg1  = 12292096;
    const long fbg4  = 12292608;
    const long fbg56 = 12293120;
    const long fbg7  = 12297216;

    // weights for G1/G2 + transposes + folded biases
    sw_A<<<dim3(4098), 256, 0, stream>>>(w_c11, w_c21, w_conv3, b_c11, b_c21, b_conv3,
                                         U + oWg1_h, U + oWg1_l, Fp + fbg1);
    transpose_split<<<dim3(32, 32, 2), 256, 0, stream>>>(x, domainX,
                                                         U + oXt_h, U + oXt_l, U + oDXt);
    prep_c<<<dim3(8, 2), 256, 0, stream>>>(w_value, b_l1down, b_l1up,
                                           b_l1down_Y, b_l1up_Y, Fp + fcX, Fp + fcY);
    prep_e<<<dim3(64, 2), 256, 0, stream>>>(w_l2down, b_l2down, Fp + fcX,
                                            w_l2down_Y, b_l2down_Y, Fp + fcY,
                                            Fp + fbg4, Fp + fbg4 + 256);

    // G1: Xt @ [c11|c21|conv3]^T, 3-pass split, K-split 8 -> f32 partials
    gmm<EPI_PART, true><<<dim3(4, 25, 8), 256, 0, stream>>>(
        U + oXt_h, U + oXt_l, 2048, 0, U + oWg1_h, U + oWg1_l, 2048, 0,
        nullptr, 0, 8, 256, Fp, nullptr, 512, 802816L, TOKENS, 512,
        nullptr, nullptr, nullptr);
    r_g1<<<dim3(3136), 256, 0, stream>>>(Fp, Fp + fbg1, pos,
        U + oQKt_h, U + oQKt_l, U + oQKt_h + 401408, U + oQKt_l + 401408, U + oVT);

    // G2: P0 = DXt @ conv3^T, K-split 4
    gmm<EPI_PART, false><<<dim3(2, 25, 4), 256, 0, stream>>>(
        U + oDXt, nullptr, 2048, 0, U + oWg1_h + 524288, nullptr, 2048, 0,
        nullptr, 0, 4, 512, Fp, nullptr, 256, 401408L, TOKENS, 256,
        nullptr, nullptr, nullptr);
    r_g2<<<dim3(1568), 256, 0, stream>>>(Fp, U + oP0);

    // remaining weights (Wg1/Xt now dead)
    sw_B<<<dim3(12306), 256, 0, stream>>>(w_value, w_l2down, w_l2down_Y, w_l2up, w_l2up_Y,
                                          w_c22, w_c12, b_l2up, b_l2up_Y, b_c22, b_c12,
                                          U + oWval, U + oWg4, U + oWg56, U + oWg7,
                                          Fp + fbg56, Fp + fbg7);

    // G3: U0 = P0 @ w_value^T (direct bf16)
    gmm<EPI_BF16, false><<<dim3(16, 25, 1), 256, 0, stream>>>(
        U + oP0, nullptr, 256, 0, U + oWval, nullptr, 256, 0,
        nullptr, 0, 1, 256, nullptr, U + oDXt, 2048, 0L, TOKENS, 2048,
        nullptr, nullptr, nullptr);

    // G4: D14 = U0 @ [l2down|l2down_Y]^T, K-split 4
    gmm<EPI_PART, false><<<dim3(4, 25, 4), 256, 0, stream>>>(
        U + oDXt, nullptr, 2048, 0, U + oWg4, nullptr, 2048, 0,
        nullptr, 0, 4, 512, Fp, nullptr, 512, 802816L, TOKENS, 512,
        nullptr, nullptr, nullptr);
    r_g4<<<dim3(3136), 256, 0, stream>>>(Fp, Fp + fbg4, U + oD14);

    // G56: dXdY[z] = D14[:, z*256:] @ l2up(_Y)^T + b (direct bf16)
    gmm<EPI_BF16, false><<<dim3(16, 25, 2), 256, 0, stream>>>(
        U + oD14, nullptr, 512, 256, U + oWg56, nullptr, 256, 524288,
        Fp + fbg56, 2048, 1, 256, nullptr, U + odXdY, 2048, 3211264L, TOKENS, 2048,
        nullptr, nullptr, nullptr);

    // G7: z=0: K2 = dX@c22 ; z=1: Q2 = dY@c12 ; K-split 4 -> partials
    gmm<EPI_PART, false><<<dim3(1, 25, 8), 256, 0, stream>>>(
        U + odXdY, nullptr, 2048, 3211264L, U + oWg7, nullptr, 2048, 262144,
        nullptr, 0, 4, 512, Fp + fpG7, nullptr, 128, 200704L, TOKENS, 128,
        nullptr, nullptr, nullptr);
    r_g7<<<dim3(1568), 256, 0, stream>>>(Fp + fpG7, Fp + fbg7,
        U + oQKt_h + 401408, U + oQKt_l + 401408, U + oQKt_h, U + oQKt_l);

    // K permute gather (both planes)
    permute_k2<<<dim3(1568), 256, 0, stream>>>(U + oQKt_h + 401408, U + oQKt_l + 401408,
                                               U + oKmT_h, U + oKmT_l);

    // logits: Q[b] @ KmT[b]^T, 3-pass split, K-split 2 -> f32 partials
    gmm<EPI_PART, true><<<dim3(4, 7, 8), 256, 0, stream>>>(
        U + oQKt_h, U + oQKt_l, 256, 100352, U + oKmT_h, U + oKmT_l, 256, 100352,
        nullptr, 0, 2, 128, Fp, nullptr, 416, 163072L, 392, 392,
        nullptr, nullptr, nullptr);
    softmax_bf16<<<dim3(1568), 64, 0, stream>>>(Fp, U + oattn);

    // PV: O[b] = attn[b] @ VT[b]^T (K=416, pads zeroed)
    gmm<EPI_BF16, false><<<dim3(2, 7, 4), 256, 0, stream>>>(
        U + oattn, nullptr, 416, 163072, U + oVT, nullptr, 416, 106496,
        nullptr, 0, 1, 416, nullptr, U + oO, 256, 100352L, 392, 256,
        nullptr, nullptr, nullptr);

    // final: z = O @ w_value^T + b_value ; out = (g*z + x)*z + x
    gmm<EPI_FINAL, false><<<dim3(16, 25, 1), 256, 0, stream>>>(
        U + oO, nullptr, 256, 0, U + oWval, nullptr, 256, 0,
        b_value, 0, 1, 256, nullptr, nullptr, 0, 0L, TOKENS, 2048,
        x, gamma, out);
}